// Round 7
// baseline (73.034 us; speedup 1.0000x reference)
//
#include <hip/hip_runtime.h>
#include <hip/hip_bf16.h>

// InfoNCE loss, B=8192, D=128, T=0.1.
// sim = normalize(E) @ normalize(E)^T / T; per-row masked exp-sums; scalar loss.
// Diagonal included in fused sums, subtracted in finalize via prep-computed
// diag[i] = exp2(dot_ii) with identical rounding to sim's operands.
//
// R7 vs R6: sim reads j-fragments DIRECTLY FROM GLOBAL (L2-resident 2MB) —
// no LDS, no __syncthreads, no staging. Tests the theory that the
// stage->barrier(vmcnt0 drain)->compute structure was the ~5x stall.
// Uncapped VGPR (R4/R6 showed 128 and 168 caps both spill). JSPLIT=64.
//
// ws layout:
//   pos_part f32[64][8192]  2MB   (sim)
//   all_part f32[64][8192]  2MB   (sim)
//   lab32    i32[8192]            (prep)
//   diag     f32[8192]            (prep)
//   lab8p    u8[8192]             (prep; 32-row-group permuted label bytes)
//   fin_s    f32[32], fin_c f32[32], ticket u32 (fin; ticket zeroed by prep)
//   Ebf      bf16[8192*128] 2MB   (prep; unit rows, j-side)
//   Ebf2     bf16[8192*128] 2MB   (prep; K_SCALE-scaled rows, i-side)

#define B_ROWS 8192
#define D_DIM 128
#define K_SCALE 14.426950408889634f  // log2(e)/0.1
#define JSPLIT 64
#define JCHUNK (B_ROWS / JSPLIT)  // 128
#define NSUB (JCHUNK / 32)        // 4
#define BM 256                    // i-rows per block = 4 waves x 64

typedef __attribute__((ext_vector_type(8))) short bf16x8;
typedef __attribute__((ext_vector_type(16))) float f32x16;
typedef __attribute__((ext_vector_type(4))) unsigned int u32x4;
typedef unsigned int u32;
typedef unsigned long long u64;

static __device__ __forceinline__ unsigned short bf16_bits(float x) {
  __hip_bfloat16 h = __float2bfloat16(x);
  unsigned short u;
  __builtin_memcpy(&u, &h, 2);
  return u;
}
static __device__ __forceinline__ float f32_from_bits(u32 b) {
  float f;
  __builtin_memcpy(&f, &b, 4);
  return f;
}
static __device__ __forceinline__ float bf16f(unsigned short u) {
  return f32_from_bits((u32)u << 16);
}

// Normalize rows in fp32; emit unit bf16 matrix (j-side), scaled bf16 matrix
// (i-side), labels (i32 + permuted u8), diag; zero the fin ticket.
__global__ __launch_bounds__(256) void prep_kernel(
    const float* __restrict__ E, const long long* __restrict__ labels,
    __hip_bfloat16* __restrict__ Ebf, __hip_bfloat16* __restrict__ Ebf2,
    int* __restrict__ lab32, unsigned char* __restrict__ lab8p,
    float* __restrict__ diag, u32* __restrict__ ticket) {
  if (blockIdx.x == 0 && threadIdx.x == 0) *ticket = 0u;
  const int wid = threadIdx.x >> 6, lane = threadIdx.x & 63;
  const int row = blockIdx.x * 4 + wid;
  const float2 v = *(const float2*)(E + (u64)row * D_DIM + lane * 2);
  float ss = v.x * v.x + v.y * v.y;
#pragma unroll
  for (int m = 1; m < 64; m <<= 1) ss += __shfl_xor(ss, m);
  const float scale = 1.0f / fmaxf(sqrtf(ss), 1e-12f);
  const unsigned short bx = bf16_bits(v.x * scale);
  const unsigned short by = bf16_bits(v.y * scale);
  ((u32*)Ebf)[(u64)row * (D_DIM / 2) + lane] = ((u32)by << 16) | bx;
  const float fx = bf16f(bx), fy = bf16f(by);
  const unsigned short axb = bf16_bits(fx * K_SCALE);
  const unsigned short ayb = bf16_bits(fy * K_SCALE);
  ((u32*)Ebf2)[(u64)row * (D_DIM / 2) + lane] = ((u32)ayb << 16) | axb;
  float dot = bf16f(axb) * fx + bf16f(ayb) * fy;
#pragma unroll
  for (int m = 1; m < 64; m <<= 1) dot += __shfl_xor(dot, m);
  if (lane == 0) diag[row] = __builtin_amdgcn_exp2f(dot);

  const int gtid = blockIdx.x * 256 + threadIdx.x;
  if (gtid < B_ROWS) {
    const int lab = (int)labels[gtid];
    lab32[gtid] = lab;
    // permute within 32-row group so reg r / hi-half reads byte h*16+r
    const int local = gtid & 31;
    const int h = (local >> 2) & 1;
    const int r = (local & 3) + 4 * (local >> 3);
    lab8p[(gtid & ~31) + h * 16 + r] = (unsigned char)lab;
  }
}

// Fused sim + exp + masked row partial sums. NO LDS, NO BARRIERS.
// 4 waves; wave w owns 64 i-rows (2 register ifrag sets) at bx*256 + w*64.
// 32x32x16 MFMA, swapped operands D[j][i] = mfma(jfrag_global, ifrag_reg):
// i = lane&31, j = (r&3)+8*(r>>2)+4*(lane>>5).
// jfrag lane l: row jbase + (l&31), k-slot 2*ks + (l>>5)  (16B dwordx4 load,
// L2-resident). grid = (32, JSPLIT); per-js partials written non-atomically.
__global__ __launch_bounds__(256) void sim_kernel(
    const __hip_bfloat16* __restrict__ Ebf,
    const __hip_bfloat16* __restrict__ Ebf2, const int* __restrict__ lab32,
    const unsigned char* __restrict__ lab8p, float* __restrict__ pos_part,
    float* __restrict__ all_part) {
  const int t = threadIdx.x;
  const int wid = t >> 6, lane = t & 63;
  const int l31 = lane & 31, hi = lane >> 5;
  const int i0w = blockIdx.x * BM + wid * 64;
  const int jbase0 = blockIdx.y * JCHUNK;

  // two register-resident i-side fragment sets (pre-scaled by K_SCALE in prep)
  bf16x8 ifragA[8], ifragB[8];
  {
    const __hip_bfloat16* srcA = Ebf2 + (u64)(i0w + l31) * D_DIM + hi * 8;
    const __hip_bfloat16* srcB = srcA + 32 * D_DIM;
#pragma unroll
    for (int ks = 0; ks < 8; ++ks) {
      ifragA[ks] = *(const bf16x8*)(srcA + ks * 16);
      ifragB[ks] = *(const bf16x8*)(srcB + ks * 16);
    }
  }
  const int labi0 = lab32[i0w + l31];
  const int labi1 = lab32[i0w + 32 + l31];

  // per-lane j-side global base: row jbase0 + l31, byte slot hi*16
  const unsigned char* jsrc =
      (const unsigned char*)Ebf + (u64)(jbase0 + l31) * 256 + hi * 16;

  float pos0 = 0.f, pos1 = 0.f, all0 = 0.f, all1 = 0.f;

#pragma unroll
  for (int jsub = 0; jsub < NSUB; ++jsub) {
    // 8 independent 16B loads: k-slots (2*ks+hi)*16 = hi*16 + ks*32
    bf16x8 jf[8];
#pragma unroll
    for (int ks = 0; ks < 8; ++ks)
      jf[ks] = *(const bf16x8*)(jsrc + (u64)jsub * (32 * 256) + ks * 32);

    f32x16 acc0 = {}, acc1 = {};
#pragma unroll
    for (int ks = 0; ks < 8; ++ks) {
      acc0 = __builtin_amdgcn_mfma_f32_32x32x16_bf16(jf[ks], ifragA[ks], acc0,
                                                     0, 0, 0);
      acc1 = __builtin_amdgcn_mfma_f32_32x32x16_bf16(jf[ks], ifragB[ks], acc1,
                                                     0, 0, 0);
    }

    const u32x4 labv =
        *(const u32x4*)(lab8p + jbase0 + jsub * 32 + hi * 16);
#pragma unroll
    for (int r = 0; r < 16; ++r) {
      const int labj = (int)((labv[r >> 2] >> ((r & 3) * 8)) & 0xff);
      const float p0 = __builtin_amdgcn_exp2f(acc0[r]);
      const float p1 = __builtin_amdgcn_exp2f(acc1[r]);
      all0 += p0;
      all1 += p1;
      pos0 += (labj == labi0) ? p0 : 0.f;
      pos1 += (labj == labi1) ? p1 : 0.f;
    }
  }

  // lanes l and l+32 hold same i, disjoint j-quarters
  pos0 += __shfl_xor(pos0, 32);
  all0 += __shfl_xor(all0, 32);
  pos1 += __shfl_xor(pos1, 32);
  all1 += __shfl_xor(all1, 32);
  if (hi == 0) {
    const u64 off = (u64)blockIdx.y * B_ROWS;
    pos_part[off + i0w + l31] = pos0;
    all_part[off + i0w + l31] = all0;
    pos_part[off + i0w + 32 + l31] = pos1;
    all_part[off + i0w + 32 + l31] = all1;
  }
}

// Single finalize: 32 blocks reduce their 256 rows; last block (ticket)
// combines the 32 partials in fixed order -> deterministic.
__global__ __launch_bounds__(256) void fin_kernel(
    const float* __restrict__ pos_part, const float* __restrict__ all_part,
    const float* __restrict__ diag, float* __restrict__ fin_s,
    float* __restrict__ fin_c, u32* __restrict__ ticket,
    float* __restrict__ out) {
  const int row = blockIdx.x * 256 + threadIdx.x;
  float ps = 0.f, as_ = 0.f;
#pragma unroll 8
  for (int js = 0; js < JSPLIT; ++js) {
    ps += pos_part[(u64)js * B_ROWS + row];
    as_ += all_part[(u64)js * B_ROWS + row];
  }
  const float d = diag[row];
  ps -= d;
  as_ -= d;
  float s = 0.f, c = 0.f;
  if (ps > 0.f) {
    s = logf(as_) - logf(ps);
    c = 1.f;
  }
#pragma unroll
  for (int m = 1; m < 64; m <<= 1) {
    s += __shfl_xor(s, m);
    c += __shfl_xor(c, m);
  }
  __shared__ float ls[4], lc[4];
  const int wid = threadIdx.x >> 6, lane = threadIdx.x & 63;
  if (lane == 0) {
    ls[wid] = s;
    lc[wid] = c;
  }
  __syncthreads();
  if (threadIdx.x == 0) {
    __hip_atomic_store(&fin_s[blockIdx.x], ls[0] + ls[1] + ls[2] + ls[3],
                       __ATOMIC_RELEASE, __HIP_MEMORY_SCOPE_AGENT);
    __hip_atomic_store(&fin_c[blockIdx.x], lc[0] + lc[1] + lc[2] + lc[3],
                       __ATOMIC_RELEASE, __HIP_MEMORY_SCOPE_AGENT);
    const u32 tk = __hip_atomic_fetch_add(ticket, 1u, __ATOMIC_ACQ_REL,
                                          __HIP_MEMORY_SCOPE_AGENT);
    if (tk == 31u) {  // last block: fixed-order combine
      float ts = 0.f, tc = 0.f;
      for (int b = 0; b < 32; ++b) {
        ts += __hip_atomic_load(&fin_s[b], __ATOMIC_ACQUIRE,
                                __HIP_MEMORY_SCOPE_AGENT);
        tc += __hip_atomic_load(&fin_c[b], __ATOMIC_ACQUIRE,
                                __HIP_MEMORY_SCOPE_AGENT);
      }
      out[0] = ts / fmaxf(tc, 1.0f);
    }
  }
}

extern "C" void kernel_launch(void* const* d_in, const int* in_sizes, int n_in,
                              void* d_out, int out_size, void* d_ws,
                              size_t ws_size, hipStream_t stream) {
  const float* E = (const float*)d_in[0];
  const long long* labels = (const long long*)d_in[1];

  float* pos_part = (float*)d_ws;                          // 64*8192
  float* all_part = pos_part + JSPLIT * B_ROWS;            // 64*8192
  int* lab32 = (int*)(all_part + JSPLIT * B_ROWS);         // 8192
  float* diag = (float*)(lab32 + B_ROWS);                  // 8192
  unsigned char* lab8p = (unsigned char*)(diag + B_ROWS);  // 8192
  float* fin_s = (float*)(lab8p + B_ROWS);                 // 32
  float* fin_c = fin_s + 32;                               // 32
  u32* ticket = (u32*)(fin_c + 32);                        // 1 (+pad)
  __hip_bfloat16* Ebf = (__hip_bfloat16*)(ticket + 4);
  __hip_bfloat16* Ebf2 = Ebf + (u64)B_ROWS * D_DIM;

  prep_kernel<<<B_ROWS / 4, 256, 0, stream>>>(E, labels, Ebf, Ebf2, lab32,
                                              lab8p, diag, ticket);
  sim_kernel<<<dim3(B_ROWS / BM, JSPLIT), 256, 0, stream>>>(
      Ebf, Ebf2, lab32, lab8p, pos_part, all_part);
  fin_kernel<<<B_ROWS / 256, 256, 0, stream>>>(pos_part, all_part, diag,
                                               fin_s, fin_c, ticket,
                                               (float*)d_out);
}

// Round 8
// 51.933 us; speedup vs baseline: 1.4063x; 1.4063x over previous
//
#include <hip/hip_runtime.h>
#include <hip/hip_bf16.h>

// InfoNCE loss, B=8192, D=128, T=0.1.
// sim = normalize(E) @ normalize(E)^T / T; per-row masked exp-sums; scalar loss.
// Diagonal included in fused sums, subtracted in finalize via prep-computed
// diag[i] = exp2(dot_ii) with identical rounding to sim's operands.
//
// R8 vs R5/R7: back to the LDS-staged structure (best), but ONE i-set per
// wave (32 rows) -> per-wave VGPR working set ~100 (ifrag 32 + acc 16 + misc)
// fits 4 waves/SIMD under __launch_bounds__(256,4) WITHOUT spilling (R4/R6
// spilled because the 2-iset set was ~160). 4-wave blocks -> 4 blocks/CU,
// 16 waves/CU target. LDS read volume doubles vs R5 (536 MB, ~8us pipe) --
// proven non-binding in R3->R5.
//
// ws layout:
//   pos_part f32[32][8192]  1MB   (sim)
//   all_part f32[32][8192]  1MB   (sim)
//   lab32    i32[8192]            (prep)
//   diag     f32[8192]            (prep)
//   lab8p    u8[8192]             (prep; 32-row-group permuted label bytes)
//   fin_s    f32[32], fin_c f32[32], ticket u32 (fin; ticket zeroed by prep)
//   Ebf      bf16[8192*128] 2MB   (prep; unit rows, j-side / LDS)
//   Ebf2     bf16[8192*128] 2MB   (prep; K_SCALE-scaled rows, i-side regs)

#define B_ROWS 8192
#define D_DIM 128
#define K_SCALE 14.426950408889634f  // log2(e)/0.1
#define JSPLIT 32
#define JCHUNK (B_ROWS / JSPLIT)  // 256
#define TILE_J 64
#define NT (JCHUNK / TILE_J)  // 4
#define BM 128                // i-rows per block = 4 waves x 32

typedef __attribute__((ext_vector_type(8))) short bf16x8;
typedef __attribute__((ext_vector_type(16))) float f32x16;
typedef __attribute__((ext_vector_type(4))) unsigned int u32x4;
typedef unsigned int u32;
typedef unsigned long long u64;

static __device__ __forceinline__ unsigned short bf16_bits(float x) {
  __hip_bfloat16 h = __float2bfloat16(x);
  unsigned short u;
  __builtin_memcpy(&u, &h, 2);
  return u;
}
static __device__ __forceinline__ float f32_from_bits(u32 b) {
  float f;
  __builtin_memcpy(&f, &b, 4);
  return f;
}
static __device__ __forceinline__ float bf16f(unsigned short u) {
  return f32_from_bits((u32)u << 16);
}

// Normalize rows in fp32; emit unit bf16 matrix (j-side), scaled bf16 matrix
// (i-side), labels (i32 + permuted u8), diag; zero the fin ticket.
__global__ __launch_bounds__(256) void prep_kernel(
    const float* __restrict__ E, const long long* __restrict__ labels,
    __hip_bfloat16* __restrict__ Ebf, __hip_bfloat16* __restrict__ Ebf2,
    int* __restrict__ lab32, unsigned char* __restrict__ lab8p,
    float* __restrict__ diag, u32* __restrict__ ticket) {
  if (blockIdx.x == 0 && threadIdx.x == 0) *ticket = 0u;
  const int wid = threadIdx.x >> 6, lane = threadIdx.x & 63;
  const int row = blockIdx.x * 4 + wid;
  const float2 v = *(const float2*)(E + (u64)row * D_DIM + lane * 2);
  float ss = v.x * v.x + v.y * v.y;
#pragma unroll
  for (int m = 1; m < 64; m <<= 1) ss += __shfl_xor(ss, m);
  const float scale = 1.0f / fmaxf(sqrtf(ss), 1e-12f);
  const unsigned short bx = bf16_bits(v.x * scale);
  const unsigned short by = bf16_bits(v.y * scale);
  ((u32*)Ebf)[(u64)row * (D_DIM / 2) + lane] = ((u32)by << 16) | bx;
  const float fx = bf16f(bx), fy = bf16f(by);
  const unsigned short axb = bf16_bits(fx * K_SCALE);
  const unsigned short ayb = bf16_bits(fy * K_SCALE);
  ((u32*)Ebf2)[(u64)row * (D_DIM / 2) + lane] = ((u32)ayb << 16) | axb;
  float dot = bf16f(axb) * fx + bf16f(ayb) * fy;
#pragma unroll
  for (int m = 1; m < 64; m <<= 1) dot += __shfl_xor(dot, m);
  if (lane == 0) diag[row] = __builtin_amdgcn_exp2f(dot);

  const int gtid = blockIdx.x * 256 + threadIdx.x;
  if (gtid < B_ROWS) {
    const int lab = (int)labels[gtid];
    lab32[gtid] = lab;
    // permute within 32-row group so reg r / hi-half reads byte h*16+r
    const int local = gtid & 31;
    const int h = (local >> 2) & 1;
    const int r = (local & 3) + 4 * (local >> 3);
    lab8p[(gtid & ~31) + h * 16 + r] = (unsigned char)lab;
  }
}

// Fused sim + exp + masked row partial sums.
// 4 waves; wave w owns 32 i-rows (ONE register ifrag set) at bx*128 + w*32.
// 32x32x16 MFMA, swapped operands D[j][i] = mfma(jfrag_lds, ifrag_reg):
// i = lane&31, j = (r&3)+8*(r>>2)+4*(lane>>5).
// grid = (64, JSPLIT); per-js partial sums written non-atomically.
__global__ __launch_bounds__(256, 4) void sim_kernel(
    const __hip_bfloat16* __restrict__ Ebf,
    const __hip_bfloat16* __restrict__ Ebf2, const int* __restrict__ lab32,
    const unsigned char* __restrict__ lab8p, float* __restrict__ pos_part,
    float* __restrict__ all_part) {
  __shared__ __align__(16) unsigned char lds[2][TILE_J * 256];

  const int t = threadIdx.x;
  const int wid = t >> 6, lane = t & 63;
  const int l31 = lane & 31, hi = lane >> 5;
  const int i0w = blockIdx.x * BM + wid * 32;
  const int jbase0 = blockIdx.y * JCHUNK;

  // register-resident i-side fragment set (pre-scaled by K_SCALE in prep)
  bf16x8 ifrag[8];
  {
    const __hip_bfloat16* src = Ebf2 + (u64)(i0w + l31) * D_DIM + hi * 8;
#pragma unroll
    for (int ks = 0; ks < 8; ++ks) ifrag[ks] = *(const bf16x8*)(src + ks * 16);
  }
  const int labi = lab32[i0w + l31];

  // swizzled LDS read addressing, folded to 2 registers:
  // offset = l31*256 + ((slot ^ key)<<4), slot = 2*ks + hi, key = lane&15
  const u32 key = lane & 15;
  const u32 M = (key & 14) << 4;
  const u32 base2 = (u32)(l31 * 256) + (((hi ^ (key & 1)) & 1) << 4);

  // staging: wave w stages LDS rows w*16+i*4+(l>>4) linearly; global slot
  // pre-swizzled: slot_g = (l&15) ^ (i*4 + (l>>4))   [m173 pattern]
  const unsigned char* gsrc[4];
  {
    const unsigned char* gb = (const unsigned char*)Ebf;
    const int l4 = lane >> 4, sl = lane & 15;
#pragma unroll
    for (int i = 0; i < 4; ++i) {
      const int rloc = wid * 16 + i * 4 + l4;
      gsrc[i] =
          gb + (u64)(jbase0 + rloc) * 256 + (u64)((sl ^ (i * 4 + l4)) * 16);
    }
  }

  auto stage = [&](int buf) {
#pragma unroll
    for (int i = 0; i < 4; ++i) {
      __builtin_amdgcn_global_load_lds(
          (const __attribute__((address_space(1))) u32*)(gsrc[i]),
          (__attribute__((address_space(3)))
               u32*)(&lds[buf][wid * 4096 + i * 1024]),
          16, 0, 0);
      gsrc[i] += TILE_J * 256;
    }
  };

  float pos0 = 0.f, all0 = 0.f;

  stage(0);
  __syncthreads();

  for (int tile = 0; tile < NT; ++tile) {
    const int cur = tile & 1;
    if (tile + 1 < NT) stage(cur ^ 1);
    const int jbase = jbase0 + tile * TILE_J;
    const unsigned char* lbuf = lds[cur];
#pragma unroll
    for (int jsub = 0; jsub < 2; ++jsub) {
      f32x16 acc = {};
#pragma unroll
      for (int ks = 0; ks < 8; ++ks) {
        bf16x8 jfrag = *(const bf16x8*)(lbuf + base2 +
                                        (((u32)(ks << 5)) ^ M) + jsub * 8192);
        acc = __builtin_amdgcn_mfma_f32_32x32x16_bf16(jfrag, ifrag[ks], acc, 0,
                                                      0, 0);
      }
      const u32x4 labv = *(const u32x4*)(lab8p + jbase + jsub * 32 + hi * 16);
#pragma unroll
      for (int r = 0; r < 16; ++r) {
        const int labj = (int)((labv[r >> 2] >> ((r & 3) * 8)) & 0xff);
        const float p = __builtin_amdgcn_exp2f(acc[r]);
        all0 += p;
        pos0 += (labj == labi) ? p : 0.f;
      }
    }
    __syncthreads();
  }

  // lanes l and l+32 hold same i, disjoint j-halves
  pos0 += __shfl_xor(pos0, 32);
  all0 += __shfl_xor(all0, 32);
  if (hi == 0) {
    const u64 off = (u64)blockIdx.y * B_ROWS;
    pos_part[off + i0w + l31] = pos0;
    all_part[off + i0w + l31] = all0;
  }
}

// Single finalize: 32 blocks reduce their 256 rows; last block (ticket)
// combines the 32 partials in fixed order -> deterministic.
__global__ __launch_bounds__(256) void fin_kernel(
    const float* __restrict__ pos_part, const float* __restrict__ all_part,
    const float* __restrict__ diag, float* __restrict__ fin_s,
    float* __restrict__ fin_c, u32* __restrict__ ticket,
    float* __restrict__ out) {
  const int row = blockIdx.x * 256 + threadIdx.x;
  float ps = 0.f, as_ = 0.f;
#pragma unroll 8
  for (int js = 0; js < JSPLIT; ++js) {
    ps += pos_part[(u64)js * B_ROWS + row];
    as_ += all_part[(u64)js * B_ROWS + row];
  }
  const float d = diag[row];
  ps -= d;
  as_ -= d;
  float s = 0.f, c = 0.f;
  if (ps > 0.f) {
    s = logf(as_) - logf(ps);
    c = 1.f;
  }
#pragma unroll
  for (int m = 1; m < 64; m <<= 1) {
    s += __shfl_xor(s, m);
    c += __shfl_xor(c, m);
  }
  __shared__ float ls[4], lc[4];
  const int wid = threadIdx.x >> 6, lane = threadIdx.x & 63;
  if (lane == 0) {
    ls[wid] = s;
    lc[wid] = c;
  }
  __syncthreads();
  if (threadIdx.x == 0) {
    __hip_atomic_store(&fin_s[blockIdx.x], ls[0] + ls[1] + ls[2] + ls[3],
                       __ATOMIC_RELEASE, __HIP_MEMORY_SCOPE_AGENT);
    __hip_atomic_store(&fin_c[blockIdx.x], lc[0] + lc[1] + lc[2] + lc[3],
                       __ATOMIC_RELEASE, __HIP_MEMORY_SCOPE_AGENT);
    const u32 tk = __hip_atomic_fetch_add(ticket, 1u, __ATOMIC_ACQ_REL,
                                          __HIP_MEMORY_SCOPE_AGENT);
    if (tk == 31u) {  // last block: fixed-order combine
      float ts = 0.f, tc = 0.f;
      for (int b = 0; b < 32; ++b) {
        ts += __hip_atomic_load(&fin_s[b], __ATOMIC_ACQUIRE,
                                __HIP_MEMORY_SCOPE_AGENT);
        tc += __hip_atomic_load(&fin_c[b], __ATOMIC_ACQUIRE,
                                __HIP_MEMORY_SCOPE_AGENT);
      }
      out[0] = ts / fmaxf(tc, 1.0f);
    }
  }
}

extern "C" void kernel_launch(void* const* d_in, const int* in_sizes, int n_in,
                              void* d_out, int out_size, void* d_ws,
                              size_t ws_size, hipStream_t stream) {
  const float* E = (const float*)d_in[0];
  const long long* labels = (const long long*)d_in[1];

  float* pos_part = (float*)d_ws;                          // 32*8192
  float* all_part = pos_part + JSPLIT * B_ROWS;            // 32*8192
  int* lab32 = (int*)(all_part + JSPLIT * B_ROWS);         // 8192
  float* diag = (float*)(lab32 + B_ROWS);                  // 8192
  unsigned char* lab8p = (unsigned char*)(diag + B_ROWS);  // 8192
  float* fin_s = (float*)(lab8p + B_ROWS);                 // 32
  float* fin_c = fin_s + 32;                               // 32
  u32* ticket = (u32*)(fin_c + 32);                        // 1 (+pad)
  __hip_bfloat16* Ebf = (__hip_bfloat16*)(ticket + 4);
  __hip_bfloat16* Ebf2 = Ebf + (u64)B_ROWS * D_DIM;

  prep_kernel<<<B_ROWS / 4, 256, 0, stream>>>(E, labels, Ebf, Ebf2, lab32,
                                              lab8p, diag, ticket);
  sim_kernel<<<dim3(B_ROWS / BM, JSPLIT), 256, 0, stream>>>(
      Ebf, Ebf2, lab32, lab8p, pos_part, all_part);
  fin_kernel<<<B_ROWS / 256, 256, 0, stream>>>(pos_part, all_part, diag,
                                               fin_s, fin_c, ticket,
                                               (float*)d_out);
}